// Round 1
// baseline (233.948 us; speedup 1.0000x reference)
//
#include <hip/hip_runtime.h>
#include <hip/hip_bf16.h>

constexpr int NB = 64;    // batch
constexpr int NL = 96;    // time / conv channels
constexpr int NC = 2048;  // feature / conv spatial
constexpr int TT = 64;    // conv spatial tile per block

// ---------------------------------------------------------------------------
// Stage 1: multi-scale moving-average decomposition.
// One thread per (b, c) column: in-register cumsum over the 96 L-positions,
// moving means for k=5/13/25 via cumsum differences + replicate-pad terms,
// softmax gate over 3 logits, write res = x - mm and mm to workspace.
// ---------------------------------------------------------------------------
__global__ __launch_bounds__(256) void decomp_kernel(
    const float* __restrict__ x,
    const float* __restrict__ gw,   // gate_w [3,1]
    const float* __restrict__ gb,   // gate_b [3]
    float* __restrict__ res,
    float* __restrict__ mm)
{
    int idx = blockIdx.x * 256 + threadIdx.x;   // = b*NC + c
    int b = idx >> 11;                          // / 2048
    size_t base = (size_t)b * (NL * NC) + (idx & (NC - 1));

    float cs[NL + 1];
    cs[0] = 0.0f;
#pragma unroll
    for (int l = 0; l < NL; ++l)
        cs[l + 1] = cs[l] + x[base + (size_t)l * NC];

    float w0 = gw[0], w1 = gw[1], w2 = gw[2];
    float b0 = gb[0], b1 = gb[1], b2 = gb[2];
    float xf = cs[1];                // x[0]   (replicate front pad)
    float xe = cs[NL] - cs[NL - 1];  // x[L-1] (replicate end pad)

#pragma unroll
    for (int l = 0; l < NL; ++l) {
        float xl = cs[l + 1] - cs[l];
        float m5, m13, m25;
#define MEANK(P, K, DST) do { \
        int lo = l - (P), hi = l + (P); \
        float s = cs[(hi > NL - 1 ? NL - 1 : hi) + 1] - cs[(lo < 0 ? 0 : lo)]; \
        if (lo < 0) s += (float)(-lo) * xf; \
        if (hi > NL - 1) s += (float)(hi - (NL - 1)) * xe; \
        DST = s * (1.0f / (K)); } while (0)
        MEANK(2, 5, m5);
        MEANK(6, 13, m13);
        MEANK(12, 25, m25);
#undef MEANK
        // gate = softmax([xl*w0+b0, xl*w1+b1, xl*w2+b2])
        float l0 = fmaf(xl, w0, b0);
        float l1 = fmaf(xl, w1, b1);
        float l2 = fmaf(xl, w2, b2);
        float mx = fmaxf(l0, fmaxf(l1, l2));
        float e0 = __expf(l0 - mx);
        float e1 = __expf(l1 - mx);
        float e2 = __expf(l2 - mx);
        float inv = 1.0f / (e0 + e1 + e2);
        float mmv = (m5 * e0 + m13 * e1 + m25 * e2) * inv;
        res[base + (size_t)l * NC] = xl - mmv;
        mm[base + (size_t)l * NC] = mmv;
    }
}

// ---------------------------------------------------------------------------
// Stage 2: two circular conv1d's sharing one weight [96,96,3].
// Block = (batch b, 64-wide spatial tile). Stage res+mm [96][66] into LDS
// (circular wrap, NC is pow2). Each wave owns 24 uniform output channels so
// weight loads are wave-uniform (scalar-load path); each thread accumulates
// 24 channels x 1 spatial position x 2 convs in registers.
// ---------------------------------------------------------------------------
__global__ __launch_bounds__(256) void conv_kernel(
    const float* __restrict__ res,
    const float* __restrict__ mm,
    const float* __restrict__ w,     // [96][96][3]
    float* __restrict__ out0,
    float* __restrict__ out1)
{
    __shared__ float sres[NL][TT + 2];
    __shared__ float smm[NL][TT + 2];

    int b = blockIdx.x;
    int t0 = blockIdx.y * TT;
    size_t bbase = (size_t)b * (NL * NC);

    for (int idx = threadIdx.x; idx < NL * (TT + 2); idx += 256) {
        int row = idx / (TT + 2);
        int col = idx - row * (TT + 2);
        int gc = (t0 - 1 + col) & (NC - 1);   // circular
        sres[row][col] = res[bbase + (size_t)row * NC + gc];
        smm[row][col]  = mm[bbase + (size_t)row * NC + gc];
    }
    __syncthreads();

    int tl = threadIdx.x & 63;                       // spatial position in tile
    int og = threadIdx.x >> 6;                       // wave id -> channel group
    int obase = __builtin_amdgcn_readfirstlane(og * 24);

    float a0[24], a1[24];
#pragma unroll
    for (int j = 0; j < 24; ++j) { a0[j] = 0.0f; a1[j] = 0.0f; }

#pragma unroll 2
    for (int i = 0; i < NL; ++i) {
        float r0 = sres[i][tl], r1 = sres[i][tl + 1], r2 = sres[i][tl + 2];
        float q0 = smm[i][tl],  q1 = smm[i][tl + 1],  q2 = smm[i][tl + 2];
#pragma unroll
        for (int j = 0; j < 24; ++j) {
            const float* wp = w + ((size_t)(obase + j) * NL + i) * 3;
            float c0 = wp[0], c1 = wp[1], c2 = wp[2];
            a0[j] = fmaf(r0, c0, fmaf(r1, c1, fmaf(r2, c2, a0[j])));
            a1[j] = fmaf(q0, c0, fmaf(q1, c1, fmaf(q2, c2, a1[j])));
        }
    }

    size_t ob = bbase + (size_t)t0 + tl;
#pragma unroll
    for (int j = 0; j < 24; ++j) {
        out0[ob + (size_t)(obase + j) * NC] = a0[j];
        out1[ob + (size_t)(obase + j) * NC] = a1[j];
    }
}

extern "C" void kernel_launch(void* const* d_in, const int* in_sizes, int n_in,
                              void* d_out, int out_size, void* d_ws, size_t ws_size,
                              hipStream_t stream)
{
    const float* x      = (const float*)d_in[0];
    const float* conv_w = (const float*)d_in[1];
    const float* gate_w = (const float*)d_in[2];
    const float* gate_b = (const float*)d_in[3];

    float* out0 = (float*)d_out;
    float* out1 = out0 + (size_t)NB * NL * NC;

    float* res = (float*)d_ws;                      // [64,96,2048] f32
    float* mm  = res + (size_t)NB * NL * NC;        // [64,96,2048] f32

    decomp_kernel<<<dim3((NB * NC) / 256), 256, 0, stream>>>(x, gate_w, gate_b, res, mm);
    conv_kernel<<<dim3(NB, NC / TT), 256, 0, stream>>>(res, mm, conv_w, out0, out1);
}

// Round 2
// 73.396 us; speedup vs baseline: 3.1875x; 3.1875x over previous
//
#include <hip/hip_runtime.h>
#include <hip/hip_bf16.h>

typedef __attribute__((ext_vector_type(8))) short short8;
typedef __attribute__((ext_vector_type(8))) unsigned short u16x8;
typedef __attribute__((ext_vector_type(4))) float f32x4;

constexpr int NB = 64;     // batch
constexpr int NL = 96;     // time / conv channels
constexpr int NC = 2048;   // feature / conv spatial
constexpr int TT = 64;     // conv spatial tile per block
constexpr int KTOT = 288;  // GEMM K = 96 ch * 3 taps, ordered k = tau*96 + i
constexpr int LROW = 104;  // padded LDS row (bf16 elems): 208 B, 52 dw % 32 = 20 -> conflict-free b128

__device__ inline unsigned short f2bf(float f) {
    union { float f; unsigned u; } v; v.f = f;
    unsigned r = v.u + 0x7fff + ((v.u >> 16) & 1);   // RNE
    return (unsigned short)(r >> 16);
}

// ---------------------------------------------------------------------------
// Stage 0: permute+convert weights: Aw[o][k], k = tau*96 + i, bf16.
// ---------------------------------------------------------------------------
__global__ void prep_aw(const float* __restrict__ w, unsigned short* __restrict__ aw)
{
    int idx = blockIdx.x * 256 + threadIdx.x;
    if (idx >= NL * KTOT) return;
    int o = idx / KTOT, k = idx - o * KTOT;
    int tau = k / NL, i = k - tau * NL;
    aw[idx] = f2bf(w[(o * NL + i) * 3 + tau]);
}

// ---------------------------------------------------------------------------
// Stage 1: decomposition. One thread per (b,c) column; writes res/mm as
// bf16 TRANSPOSED [b][c][l] (a contiguous 192 B block per thread) so the
// conv's B-operand tiles are contiguous in global memory.
// ---------------------------------------------------------------------------
__global__ __launch_bounds__(256) void decomp_kernel(
    const float* __restrict__ x,
    const float* __restrict__ gw,
    const float* __restrict__ gb,
    unsigned short* __restrict__ resT,   // [64][2048][96] bf16
    unsigned short* __restrict__ mmT)
{
    int idx = blockIdx.x * 256 + threadIdx.x;   // = b*NC + c
    int b = idx >> 11;
    size_t base = (size_t)b * (NL * NC) + (idx & (NC - 1));

    float cs[NL + 1];
    cs[0] = 0.0f;
#pragma unroll
    for (int l = 0; l < NL; ++l)
        cs[l + 1] = cs[l] + x[base + (size_t)l * NC];

    float w0 = gw[0], w1 = gw[1], w2 = gw[2];
    float b0 = gb[0], b1 = gb[1], b2 = gb[2];
    float xf = cs[1];
    float xe = cs[NL] - cs[NL - 1];

    u16x8 ro[12], mo[12];
#pragma unroll
    for (int l = 0; l < NL; ++l) {
        float xl = cs[l + 1] - cs[l];
        float m5, m13, m25;
#define MEANK(P, K, DST) do { \
        int lo = l - (P), hi = l + (P); \
        float s = cs[(hi > NL - 1 ? NL - 1 : hi) + 1] - cs[(lo < 0 ? 0 : lo)]; \
        if (lo < 0) s += (float)(-lo) * xf; \
        if (hi > NL - 1) s += (float)(hi - (NL - 1)) * xe; \
        DST = s * (1.0f / (K)); } while (0)
        MEANK(2, 5, m5);
        MEANK(6, 13, m13);
        MEANK(12, 25, m25);
#undef MEANK
        float l0 = fmaf(xl, w0, b0);
        float l1 = fmaf(xl, w1, b1);
        float l2 = fmaf(xl, w2, b2);
        float mx = fmaxf(l0, fmaxf(l1, l2));
        float e0 = __expf(l0 - mx);
        float e1 = __expf(l1 - mx);
        float e2 = __expf(l2 - mx);
        float inv = 1.0f / (e0 + e1 + e2);
        float mmv = (m5 * e0 + m13 * e1 + m25 * e2) * inv;
        ro[l >> 3][l & 7] = f2bf(xl - mmv);
        mo[l >> 3][l & 7] = f2bf(mmv);
    }

    size_t ob = (size_t)idx * NL;
#pragma unroll
    for (int v = 0; v < 12; ++v) {
        *(u16x8*)(resT + ob + v * 8) = ro[v];
        *(u16x8*)(mmT  + ob + v * 8) = mo[v];
    }
}

// ---------------------------------------------------------------------------
// Stage 2: both circular convs as one bf16 MFMA GEMM.
//   out[o][t] = sum_k Aw[o][k] * B[k][t],  B[k=tau*96+i][t] = X[i][t+tau-1]
// Block = (batch, 64-col tile). LDS holds X tiles transposed [t][i] (rows
// padded to 104) so every B fragment is one conflict-free ds_read_b128.
// 4 waves: wave = (mg = rows mg*48..+47) x (ng = cols ng*32..+31); each wave
// 3 m-tiles x 2 n-tiles x 2 signals of 16x16x32 accumulators.
// A fragments prefetched from global (L2-hot 55 KB) one k-step ahead.
// ---------------------------------------------------------------------------
__global__ __launch_bounds__(256) void conv_mfma(
    const unsigned short* __restrict__ resT,
    const unsigned short* __restrict__ mmT,
    const unsigned short* __restrict__ aw,
    float* __restrict__ out0,
    float* __restrict__ out1)
{
    __shared__ unsigned short sx[2][TT + 2][LROW];

    int b = blockIdx.x;
    int t0 = blockIdx.y * TT;
    size_t xb = (size_t)b * NC * NL;

    // stage: 2 sigs x 66 rows x 12 chunks of 16 B
    for (int idx = threadIdx.x; idx < 2 * (TT + 2) * 12; idx += 256) {
        int sig = idx / ((TT + 2) * 12);
        int rem = idx - sig * (TT + 2) * 12;
        int row = rem / 12, ch = rem - row * 12;
        int t = (t0 - 1 + row) & (NC - 1);
        const unsigned short* src = sig ? mmT : resT;
        u16x8 v = *(const u16x8*)(src + xb + (size_t)t * NL + ch * 8);
        *(u16x8*)(&sx[sig][row][ch * 8]) = v;
    }

    int lane = threadIdx.x & 63;
    int wv = threadIdx.x >> 6;
    int mg = wv & 1, ng = wv >> 1;
    int lr = lane & 15, lk = lane >> 4;

    f32x4 acc[3][2][2] = {};

    const unsigned short* abase = aw + (size_t)(mg * 48 + lr) * KTOT + lk * 8;
    short8 aCur[3], aNxt[3];
#pragma unroll
    for (int mt = 0; mt < 3; ++mt)
        aCur[mt] = *(const short8*)(abase + mt * 16 * KTOT);

    __syncthreads();

#pragma unroll
    for (int ks = 0; ks < 9; ++ks) {
        if (ks < 8) {
#pragma unroll
            for (int mt = 0; mt < 3; ++mt)
                aNxt[mt] = *(const short8*)(abase + mt * 16 * KTOT + (ks + 1) * 32);
        }
        const int tau = ks / 3;
        const int i0 = (ks - tau * 3) * 32;
        short8 bf[2][2];
#pragma unroll
        for (int nt = 0; nt < 2; ++nt) {
            int r = ng * 32 + nt * 16 + lr + tau;   // LDS row = local t + tau
#pragma unroll
            for (int sig = 0; sig < 2; ++sig)
                bf[nt][sig] = *(const short8*)(&sx[sig][r][i0 + lk * 8]);
        }
#pragma unroll
        for (int mt = 0; mt < 3; ++mt)
#pragma unroll
            for (int nt = 0; nt < 2; ++nt)
#pragma unroll
                for (int sig = 0; sig < 2; ++sig)
                    acc[mt][nt][sig] = __builtin_amdgcn_mfma_f32_16x16x32_bf16(
                        aCur[mt], bf[nt][sig], acc[mt][nt][sig], 0, 0, 0);
#pragma unroll
        for (int mt = 0; mt < 3; ++mt) aCur[mt] = aNxt[mt];
    }

    // epilogue: C/D layout col = lane&15, row = (lane>>4)*4 + reg
    size_t ob = (size_t)b * NL * NC;
    int tw = t0 + ng * 32 + lr;
#pragma unroll
    for (int mt = 0; mt < 3; ++mt) {
        int o0 = mg * 48 + mt * 16 + lk * 4;
#pragma unroll
        for (int nt = 0; nt < 2; ++nt) {
#pragma unroll
            for (int r4 = 0; r4 < 4; ++r4) {
                out0[ob + (size_t)(o0 + r4) * NC + tw + nt * 16] = acc[mt][nt][0][r4];
                out1[ob + (size_t)(o0 + r4) * NC + tw + nt * 16] = acc[mt][nt][1][r4];
            }
        }
    }
}

extern "C" void kernel_launch(void* const* d_in, const int* in_sizes, int n_in,
                              void* d_out, int out_size, void* d_ws, size_t ws_size,
                              hipStream_t stream)
{
    const float* x      = (const float*)d_in[0];
    const float* conv_w = (const float*)d_in[1];
    const float* gate_w = (const float*)d_in[2];
    const float* gate_b = (const float*)d_in[3];

    float* out0 = (float*)d_out;
    float* out1 = out0 + (size_t)NB * NL * NC;

    unsigned short* resT = (unsigned short*)d_ws;          // [64][2048][96] bf16
    unsigned short* mmT  = resT + (size_t)NB * NC * NL;
    unsigned short* awb  = mmT  + (size_t)NB * NC * NL;    // [96][288] bf16

    prep_aw<<<dim3((NL * KTOT + 255) / 256), 256, 0, stream>>>(conv_w, awb);
    decomp_kernel<<<dim3((NB * NC) / 256), 256, 0, stream>>>(x, gate_w, gate_b, resT, mmT);
    conv_mfma<<<dim3(NB, NC / TT), 256, 0, stream>>>(resT, mmT, awb, out0, out1);
}

// Round 3
// 60.691 us; speedup vs baseline: 3.8547x; 1.2093x over previous
//
#include <hip/hip_runtime.h>
#include <hip/hip_bf16.h>

typedef __attribute__((ext_vector_type(8))) short short8;
typedef __attribute__((ext_vector_type(8))) unsigned short u16x8;
typedef __attribute__((ext_vector_type(4))) float f32x4;

constexpr int NB = 64;     // batch
constexpr int NL = 96;     // time / conv channels
constexpr int NC = 2048;   // feature / conv spatial
constexpr int TT = 64;     // conv spatial tile per block
constexpr int KTOT = 288;  // GEMM K = 96 ch * 3 taps, k = tau*96 + i
constexpr int LROW = 104;  // LDS row pitch (bf16): 208 B, 16B-aligned rows, min-phase b128 reads

__device__ inline unsigned short f2bf(float f) {
    union { float f; unsigned u; } v; v.f = f;
    unsigned r = v.u + 0x7fff + ((v.u >> 16) & 1);   // RNE
    return (unsigned short)(r >> 16);
}

// ---------------------------------------------------------------------------
// Weight permute+convert: Aw[o][k], k = tau*96 + i, bf16.
// ---------------------------------------------------------------------------
__global__ void prep_aw(const float* __restrict__ w, unsigned short* __restrict__ aw)
{
    int idx = blockIdx.x * 256 + threadIdx.x;
    if (idx >= NL * KTOT) return;
    int o = idx / KTOT, k = idx - o * KTOT;
    int tau = k / NL, i = k - tau * NL;
    aw[idx] = f2bf(w[(o * NL + i) * 3 + tau]);
}

// ---------------------------------------------------------------------------
// Decomp for one (column c, l-chunk Q*32..Q*32+31): local cumsum over the
// needed row range (compile-time Q -> all indices static, stays in VGPRs),
// moving means + softmax gate, write res/mm bf16 directly into LDS B-tiles.
// ---------------------------------------------------------------------------
template<int Q>
__device__ __forceinline__ void decomp_chunk(
    const float* __restrict__ xc,          // &x[b][0][t], stride NC
    int c,
    float w0, float w1, float w2, float b0, float b1, float b2,
    unsigned short (*sb)[TT + 2][LROW])    // sb[sig][row=c][i=l]
{
    constexpr int R0 = (Q == 0) ? 0 : 32 * Q - 12;
    constexpr int R1 = (Q == 2) ? 95 : 32 * Q + 43;
    constexpr int NR = R1 - R0 + 1;        // 44 / 56 / 44

    float lcs[NR + 1];
    lcs[0] = 0.0f;
#pragma unroll
    for (int r = 0; r < NR; ++r)
        lcs[r + 1] = lcs[r] + xc[(size_t)(R0 + r) * NC];

    float xf = lcs[1];                 // x[0]  (valid when Q==0)
    float xe = lcs[NR] - lcs[NR - 1];  // x[95] (valid when Q==2)

    u16x8 ro[4], mo[4];
#pragma unroll
    for (int j = 0; j < 32; ++j) {
        const int l = 32 * Q + j;
        float xl = lcs[l - R0 + 1] - lcs[l - R0];
        float m5, m13, m25;
#define MEANK(P, K, DST) do { \
        int lo = l - (P), hi = l + (P); \
        int loc = (lo < 0 ? 0 : lo) - R0, hic = (hi > 95 ? 95 : hi) - R0; \
        float s = lcs[hic + 1] - lcs[loc]; \
        if (lo < 0) s += (float)(-lo) * xf; \
        if (hi > 95) s += (float)(hi - 95) * xe; \
        DST = s * (1.0f / (K)); } while (0)
        MEANK(2, 5, m5);
        MEANK(6, 13, m13);
        MEANK(12, 25, m25);
#undef MEANK
        float l0 = fmaf(xl, w0, b0);
        float l1 = fmaf(xl, w1, b1);
        float l2 = fmaf(xl, w2, b2);
        float mx = fmaxf(l0, fmaxf(l1, l2));
        float e0 = __expf(l0 - mx);
        float e1 = __expf(l1 - mx);
        float e2 = __expf(l2 - mx);
        float inv = 1.0f / (e0 + e1 + e2);
        float mmv = (m5 * e0 + m13 * e1 + m25 * e2) * inv;
        ro[j >> 3][j & 7] = f2bf(xl - mmv);
        mo[j >> 3][j & 7] = f2bf(mmv);
    }
#pragma unroll
    for (int v = 0; v < 4; ++v) {
        *(u16x8*)(&sb[0][c][32 * Q + v * 8]) = ro[v];
        *(u16x8*)(&sb[1][c][32 * Q + v * 8]) = mo[v];
    }
}

// ---------------------------------------------------------------------------
// Fused kernel: block = (batch b, 64-wide spatial tile).
// Phase 1: 198 units (66 cols x 3 l-chunks) decompose x -> res/mm bf16 in LDS.
// Phase 2: both circular convs as one bf16 MFMA GEMM,
//   out[o][t] = sum_k Aw[o][k] * B[k][t], B[k=tau*96+i][t] = X[i][t+tau-1].
// 4 waves: (mg: 48 out-rows) x (ng: 32 cols); 3x2x2 16x16x32 accs per wave.
// ---------------------------------------------------------------------------
__global__ __launch_bounds__(256, 3) void fused_kernel(
    const float* __restrict__ x,
    const float* __restrict__ gw,
    const float* __restrict__ gb,
    const unsigned short* __restrict__ aw,
    float* __restrict__ out0,
    float* __restrict__ out1)
{
    __shared__ unsigned short sx[2][TT + 2][LROW];

    int b = blockIdx.x;
    int t0 = blockIdx.y * TT;

    int lane = threadIdx.x & 63;
    int wv = threadIdx.x >> 6;
    int mg = wv & 1, ng = wv >> 1;
    int lr = lane & 15, lk = lane >> 4;

    // A-fragment prefetch (L2-hot 55 KB) — issued before decomp VALU work
    const unsigned short* abase = aw + (size_t)(mg * 48 + lr) * KTOT + lk * 8;
    short8 aCur[3], aNxt[3];
#pragma unroll
    for (int mt = 0; mt < 3; ++mt)
        aCur[mt] = *(const short8*)(abase + mt * 16 * KTOT);

    // ---- Phase 1: fused decomposition into LDS ----
    int unit = threadIdx.x;
    if (unit < 198) {
        int q = unit / 66;
        int c = unit - q * 66;
        int t = (t0 - 1 + c) & (NC - 1);        // circular halo
        const float* xc = x + (size_t)b * NL * NC + t;
        float w0 = gw[0], w1 = gw[1], w2 = gw[2];
        float b0 = gb[0], b1 = gb[1], b2 = gb[2];
        if (q == 0)      decomp_chunk<0>(xc, c, w0, w1, w2, b0, b1, b2, sx);
        else if (q == 1) decomp_chunk<1>(xc, c, w0, w1, w2, b0, b1, b2, sx);
        else             decomp_chunk<2>(xc, c, w0, w1, w2, b0, b1, b2, sx);
    }
    __syncthreads();

    // ---- Phase 2: MFMA GEMM ----
    f32x4 acc[3][2][2] = {};

#pragma unroll
    for (int ks = 0; ks < 9; ++ks) {
        if (ks < 8) {
#pragma unroll
            for (int mt = 0; mt < 3; ++mt)
                aNxt[mt] = *(const short8*)(abase + mt * 16 * KTOT + (ks + 1) * 32);
        }
        const int tau = ks / 3;
        const int i0 = (ks - tau * 3) * 32;
        short8 bf[2][2];
#pragma unroll
        for (int nt = 0; nt < 2; ++nt) {
            int r = ng * 32 + nt * 16 + lr + tau;   // LDS row = local t + tau
#pragma unroll
            for (int sig = 0; sig < 2; ++sig)
                bf[nt][sig] = *(const short8*)(&sx[sig][r][i0 + lk * 8]);
        }
#pragma unroll
        for (int mt = 0; mt < 3; ++mt)
#pragma unroll
            for (int nt = 0; nt < 2; ++nt)
#pragma unroll
                for (int sig = 0; sig < 2; ++sig)
                    acc[mt][nt][sig] = __builtin_amdgcn_mfma_f32_16x16x32_bf16(
                        aCur[mt], bf[nt][sig], acc[mt][nt][sig], 0, 0, 0);
#pragma unroll
        for (int mt = 0; mt < 3; ++mt) aCur[mt] = aNxt[mt];
    }

    // epilogue: C/D layout col = lane&15, row = (lane>>4)*4 + reg
    size_t ob = (size_t)b * NL * NC;
    int tw = t0 + ng * 32 + lr;
#pragma unroll
    for (int mt = 0; mt < 3; ++mt) {
        int o0 = mg * 48 + mt * 16 + lk * 4;
#pragma unroll
        for (int nt = 0; nt < 2; ++nt) {
#pragma unroll
            for (int r4 = 0; r4 < 4; ++r4) {
                out0[ob + (size_t)(o0 + r4) * NC + tw + nt * 16] = acc[mt][nt][0][r4];
                out1[ob + (size_t)(o0 + r4) * NC + tw + nt * 16] = acc[mt][nt][1][r4];
            }
        }
    }
}

extern "C" void kernel_launch(void* const* d_in, const int* in_sizes, int n_in,
                              void* d_out, int out_size, void* d_ws, size_t ws_size,
                              hipStream_t stream)
{
    const float* x      = (const float*)d_in[0];
    const float* conv_w = (const float*)d_in[1];
    const float* gate_w = (const float*)d_in[2];
    const float* gate_b = (const float*)d_in[3];

    float* out0 = (float*)d_out;
    float* out1 = out0 + (size_t)NB * NL * NC;

    unsigned short* awb = (unsigned short*)d_ws;   // [96][288] bf16

    prep_aw<<<dim3((NL * KTOT + 255) / 256), 256, 0, stream>>>(conv_w, awb);
    fused_kernel<<<dim3(NB, NC / TT), 256, 0, stream>>>(x, gate_w, gate_b, awb, out0, out1);
}